// Round 4
// baseline (63.277 us; speedup 1.0000x reference)
//
#include <hip/hip_runtime.h>
#include <hip/hip_bf16.h>

#define BB 16
#define NN 512
#define DIN 256
#define DOUT 256
#define HH 8
#define HD 32
#define EE 131072
#define MM (BB*NN)    // 8192 rows
#define BH (BB*HH)    // 128

typedef unsigned short ushort_t;
typedef __attribute__((ext_vector_type(8))) short bf16x8;
typedef __attribute__((ext_vector_type(4))) float f32x4;

__device__ __forceinline__ unsigned short f2bf(float f) {
    unsigned int u = __float_as_uint(f);
    unsigned int r = (u + 0x7fffu + ((u >> 16) & 1u)) >> 16;
    return (unsigned short)r;
}

// ---------------- fused prep: zero maskT | h fp32->bf16 | weight transpose+convert ----------------
// blocks [0,128): zero maskT; [128,1152): h2bf; [1152,2176): wprep
__global__ __launch_bounds__(256) void prep(
    const float* __restrict__ h,
    const float* __restrict__ Wq, const float* __restrict__ Wk,
    const float* __restrict__ Wv, const float* __restrict__ Wo,
    unsigned int* __restrict__ maskT, ushort_t* __restrict__ hb,
    ushort_t* __restrict__ Wt, ushort_t* __restrict__ Wot) {
    const int bid = blockIdx.x;
    const int t = threadIdx.x;
    if (bid < 128) {
        uint4 z = {0u, 0u, 0u, 0u};
        ((uint4*)maskT)[bid * 256 + t] = z;   // 32768 uint4 = 512 KB
    } else if (bid < 1152) {
        int chunk = (bid - 128) * 256 + t;    // 262144 chunks of 8 floats
        float4 a = *(const float4*)(h + (size_t)chunk * 8);
        float4 b = *(const float4*)(h + (size_t)chunk * 8 + 4);
        ushort_t o[8] = {f2bf(a.x), f2bf(a.y), f2bf(a.z), f2bf(a.w),
                         f2bf(b.x), f2bf(b.y), f2bf(b.z), f2bf(b.w)};
        *(uint4*)(hb + (size_t)chunk * 8) = *(const uint4*)o;
    } else {
        int tg = (bid - 1152) * 256 + t;      // 262144 = 1024 rows x 256 cols
        int n = tg >> 8, k = tg & 255;
        if (n < 768) {
            const float* W = (n < 256) ? Wq : (n < 512) ? Wk : Wv;
            Wt[(size_t)n * 256 + k] = f2bf(W[(size_t)k * 256 + (n & 255)]);
        } else {
            int nn = n - 768;
            Wot[(size_t)nn * 256 + k] = f2bf(Wo[(size_t)k * 256 + nn]);
        }
    }
}

// ---------------- mask build: transposed bitmask maskT[b][word][row] ----------------
__global__ void mask_build(const int* __restrict__ src, const int* __restrict__ dst,
                           unsigned int* __restrict__ maskT) {
    int t = blockIdx.x * 256 + threadIdx.x;
    if (t < EE) {
        int s = src[t], d = dst[t];
        int b = s / NN, r = s % NN, c = d % NN;
        atomicOr(&maskT[((size_t)(b * 16) + (c >> 5)) * NN + r], 1u << (c & 31));
    }
    if (t < MM) {
        int b = t / NN, r = t % NN;
        atomicOr(&maskT[((size_t)(b * 16) + (r >> 5)) * NN + r], 1u << (r & 31));
    }
}

// ---------------- bf16 MFMA GEMM: C[M x N] = A[M x 256] * Bt[N x 256]^T + bias ----------------
// MODE 0: N=768 fused QKV -> scatter to qb/kb (B,H,N,HD) and vT (B,H,HD,N), bf16
// MODE 1: N=256 output projection -> fp32 row-major out
template<int MODE>
__global__ __launch_bounds__(256) void gemm_mfma(
    const ushort_t* __restrict__ A, const ushort_t* __restrict__ Bt,
    const float* __restrict__ b0, const float* __restrict__ b1, const float* __restrict__ b2,
    ushort_t* __restrict__ qb, ushort_t* __restrict__ kb, ushort_t* __restrict__ vT,
    float* __restrict__ fout) {
    __shared__ ushort_t As[64][72];
    __shared__ ushort_t Bs[64][72];
    const int t = threadIdx.x;
    const int m0 = blockIdx.x * 64, n0 = blockIdx.y * 64;
    const int wid = t >> 6, lane = t & 63, g = lane >> 4, c = lane & 15;
    const int wr = wid >> 1, wc = wid & 1;

    f32x4 acc00 = {0.f,0.f,0.f,0.f}, acc01 = acc00, acc10 = acc00, acc11 = acc00;

    for (int k0 = 0; k0 < 256; k0 += 64) {
        #pragma unroll
        for (int i = 0; i < 2; ++i) {
            int f = t + i * 256;
            int row = f >> 3, c16 = f & 7;
            *(uint4*)&As[row][c16 * 8] = *(const uint4*)(A  + (size_t)(m0 + row) * 256 + k0 + c16 * 8);
            *(uint4*)&Bs[row][c16 * 8] = *(const uint4*)(Bt + (size_t)(n0 + row) * 256 + k0 + c16 * 8);
        }
        __syncthreads();
        #pragma unroll
        for (int kk = 0; kk < 2; ++kk) {
            bf16x8 a0 = *(const bf16x8*)&As[wr * 32 + c][kk * 32 + 8 * g];
            bf16x8 a1 = *(const bf16x8*)&As[wr * 32 + 16 + c][kk * 32 + 8 * g];
            bf16x8 bb0 = *(const bf16x8*)&Bs[wc * 32 + c][kk * 32 + 8 * g];
            bf16x8 bb1 = *(const bf16x8*)&Bs[wc * 32 + 16 + c][kk * 32 + 8 * g];
            acc00 = __builtin_amdgcn_mfma_f32_16x16x32_bf16(a0, bb0, acc00, 0, 0, 0);
            acc01 = __builtin_amdgcn_mfma_f32_16x16x32_bf16(a0, bb1, acc01, 0, 0, 0);
            acc10 = __builtin_amdgcn_mfma_f32_16x16x32_bf16(a1, bb0, acc10, 0, 0, 0);
            acc11 = __builtin_amdgcn_mfma_f32_16x16x32_bf16(a1, bb1, acc11, 0, 0, 0);
        }
        __syncthreads();
    }

    #pragma unroll
    for (int mi = 0; mi < 2; ++mi) {
        #pragma unroll
        for (int nj = 0; nj < 2; ++nj) {
            const f32x4 av = (mi == 0) ? (nj == 0 ? acc00 : acc01) : (nj == 0 ? acc10 : acc11);
            const int m_base = m0 + wr * 32 + mi * 16 + 4 * g;
            const int n_base = n0 + wc * 32 + nj * 16;
            if (MODE == 1) {
                const float bias = b0[n_base + c];
                #pragma unroll
                for (int r = 0; r < 4; ++r)
                    fout[(size_t)(m_base + r) * 256 + n_base + c] = av[r] + bias;
            } else {
                const int z = n_base >> 8, nn = n_base & 255;
                const int hh = nn >> 5, hd = (nn & 31) + c;
                const float* bp = (z == 0) ? b0 : (z == 1) ? b1 : b2;
                const float bias = bp[nn + c];
                const int b = m_base >> 9, nrow = m_base & 511;
                if (z == 2) {
                    #pragma unroll
                    for (int r = 0; r < 4; ++r)
                        vT[(((size_t)(b * 8 + hh)) * 32 + hd) * 512 + nrow + r] = f2bf(av[r] + bias);
                } else {
                    ushort_t* dst = (z == 0) ? qb : kb;
                    #pragma unroll
                    for (int r = 0; r < 4; ++r)
                        dst[(((size_t)(b * 8 + hh)) * 512 + nrow + r) * 32 + hd] = f2bf(av[r] + bias);
                }
            }
        }
    }
}

// ---------------- MFMA flash attention, no K/V staging (L2-resident), no barriers ----------------
__global__ __launch_bounds__(256) void attn_mfma(
    const ushort_t* __restrict__ qb, const ushort_t* __restrict__ kb,
    const ushort_t* __restrict__ vT, const unsigned int* __restrict__ maskT,
    ushort_t* __restrict__ attnb) {
    __shared__ ushort_t Ps[4][640];     // per-wave P scratch [16][40]

    const int t = threadIdx.x;
    const int bh = blockIdx.x;
    const int q0 = blockIdx.y * 64;
    const int b = bh >> 3, h = bh & 7;
    const int wid = t >> 6, lane = t & 63;
    const int g = lane >> 4, c = lane & 15;

    const ushort_t* kgb = kb + (size_t)bh * NN * HD;   // [key][32]
    const ushort_t* vgb = vT + (size_t)bh * HD * NN;   // [dim][512]

    bf16x8 qa = *(const bf16x8*)(qb + ((size_t)bh * NN + q0 + wid * 16 + c) * HD + 8 * g);

    const f32x4 zf = {0.f, 0.f, 0.f, 0.f};
    f32x4 acc0 = zf, acc1 = zf;
    float lsum[4] = {0.f, 0.f, 0.f, 0.f};
    ushort_t* Pw = &Ps[wid][0];
    const float SCALE = 0.17677669529663687f;  // 1/sqrt(32)
    const size_t mbase = (size_t)b * 8192 + q0 + wid * 16 + 4 * g;

    #pragma unroll 4
    for (int kt = 0; kt < 16; ++kt) {
        uint4 mw = *(const uint4*)(maskT + mbase + (size_t)kt * 512);
        bf16x8 kb0 = *(const bf16x8*)(kgb + (size_t)(kt * 32 + c) * HD + 8 * g);
        bf16x8 kb1 = *(const bf16x8*)(kgb + (size_t)(kt * 32 + 16 + c) * HD + 8 * g);
        f32x4 s0 = __builtin_amdgcn_mfma_f32_16x16x32_bf16(qa, kb0, zf, 0, 0, 0);
        f32x4 s1 = __builtin_amdgcn_mfma_f32_16x16x32_bf16(qa, kb1, zf, 0, 0, 0);
        const unsigned int* mwp = (const unsigned int*)&mw;
        #pragma unroll
        for (int r = 0; r < 4; ++r) {
            unsigned int w = mwp[r];
            // fixed-offset softmax: logits bounded << 16, final /l renormalizes
            float p0 = ((w >> c) & 1u)        ? __expf(fmaf(s0[r], SCALE, -16.0f)) : 0.f;
            float p1 = ((w >> (16 + c)) & 1u) ? __expf(fmaf(s1[r], SCALE, -16.0f)) : 0.f;
            lsum[r] += p0 + p1;
            Pw[(4 * g + r) * 40 + c]      = f2bf(p0);
            Pw[(4 * g + r) * 40 + 16 + c] = f2bf(p1);
        }
        bf16x8 pa  = *(const bf16x8*)&Pw[c * 40 + 8 * g];
        bf16x8 vb0 = *(const bf16x8*)(vgb + (size_t)c * NN + kt * 32 + 8 * g);
        bf16x8 vb1 = *(const bf16x8*)(vgb + (size_t)(16 + c) * NN + kt * 32 + 8 * g);
        acc0 = __builtin_amdgcn_mfma_f32_16x16x32_bf16(pa, vb0, acc0, 0, 0, 0);
        acc1 = __builtin_amdgcn_mfma_f32_16x16x32_bf16(pa, vb1, acc1, 0, 0, 0);
    }

    #pragma unroll
    for (int r = 0; r < 4; ++r) {
        float l = lsum[r];
        l += __shfl_xor(l, 1);
        l += __shfl_xor(l, 2);
        l += __shfl_xor(l, 4);
        l += __shfl_xor(l, 8);
        lsum[r] = l;
    }
    #pragma unroll
    for (int r = 0; r < 4; ++r) {
        float rl = 1.0f / lsum[r];
        ushort_t* orow = attnb + ((size_t)(b * NN + q0 + wid * 16 + 4 * g + r)) * DOUT + h * HD;
        orow[c]      = f2bf(acc0[r] * rl);
        orow[16 + c] = f2bf(acc1[r] * rl);
    }
}

extern "C" void kernel_launch(void* const* d_in, const int* in_sizes, int n_in,
                              void* d_out, int out_size, void* d_ws, size_t ws_size,
                              hipStream_t stream) {
    const float* hin = (const float*)d_in[0];
    const int* src   = (const int*)d_in[1];
    const int* dst   = (const int*)d_in[2];
    const float* Wq  = (const float*)d_in[3];
    const float* bq  = (const float*)d_in[4];
    const float* Wk  = (const float*)d_in[5];
    const float* bk  = (const float*)d_in[6];
    const float* Wv  = (const float*)d_in[7];
    const float* bv  = (const float*)d_in[8];
    const float* Wo  = (const float*)d_in[9];
    const float* bo  = (const float*)d_in[10];

    char* ws = (char*)d_ws;
    unsigned int* maskT = (unsigned int*)ws;                    // 512 KB
    ushort_t* hb    = (ushort_t*)(ws + 524288);                 // 4 MB
    ushort_t* qb    = (ushort_t*)(ws + 4718592);                // 4 MB
    ushort_t* kb    = (ushort_t*)(ws + 8912896);                // 4 MB
    ushort_t* vT    = (ushort_t*)(ws + 13107200);               // 4 MB
    ushort_t* attnb = (ushort_t*)(ws + 17301504);               // 4 MB
    ushort_t* Wt    = (ushort_t*)(ws + 21495808);               // 384 KB
    ushort_t* Wot   = (ushort_t*)(ws + 21889024);               // 128 KB
    float* out = (float*)d_out;

    prep<<<2176, 256, 0, stream>>>(hin, Wq, Wk, Wv, Wo, maskT, hb, Wt, Wot);
    mask_build<<<(EE + 255) / 256, 256, 0, stream>>>(src, dst, maskT);
    gemm_mfma<0><<<dim3(MM / 64, 768 / 64), 256, 0, stream>>>(hb, Wt, bq, bk, bv,
                                                              qb, kb, vT, nullptr);
    attn_mfma<<<dim3(BH, NN / 64), 256, 0, stream>>>(qb, kb, vT, maskT, attnb);
    gemm_mfma<1><<<dim3(MM / 64, 256 / 64), 256, 0, stream>>>(attnb, Wot, bo, nullptr, nullptr,
                                                              nullptr, nullptr, nullptr, out);
}